// Round 4
// baseline (727.212 us; speedup 1.0000x reference)
//
#include <hip/hip_runtime.h>
#include <hip/hip_bf16.h>
#include <math.h>

typedef __attribute__((ext_vector_type(8))) short short8;
typedef __attribute__((ext_vector_type(4))) float f32x4;

// Problem constants: B=4, S=1024, H=16, d_k=64, d_model=1024.

static __device__ __forceinline__ unsigned short f2bf(float x) {
  union { float f; unsigned u; } v; v.f = x;
  unsigned r = v.u + 0x7fffu + ((v.u >> 16) & 1u);   // RNE
  return (unsigned short)(r >> 16);
}

// lgkmcnt-only barrier: drains LDS traffic (cross-wave LDS reads safe) but
// leaves global register-prefetch loads in flight across the barrier.
static __device__ __forceinline__ void bar_lds() {
  asm volatile("s_waitcnt lgkmcnt(0)" ::: "memory");
  __builtin_amdgcn_s_barrier();
}

// ---------------------------------------------------------------------------
// Kernel 0: prep — transpose+convert weights to bf16.
//   blocks [0,3072): Wq/Wk/Wv -> wt[which][h][n=64][d=1024]  (6.3 MB)
//   blocks [3072,4096): Wo -> wot[n=1024][k=1024]            (2.1 MB)
// ---------------------------------------------------------------------------
__global__ __launch_bounds__(256) void prep_wt(
    const float* __restrict__ Wq, const float* __restrict__ Wk,
    const float* __restrict__ Wv, const float* __restrict__ Wo,
    unsigned short* __restrict__ wt, unsigned short* __restrict__ wot) {
  if (blockIdx.x < 3072) {
    int idx = blockIdx.x * 256 + threadIdx.x;   // [0, 786432)
    int which = idx >> 18;
    int rem = idx & 262143;
    int h = rem >> 14;
    int d = (rem >> 4) & 1023;
    int n4 = rem & 15;
    const float* W = which == 0 ? Wq : (which == 1 ? Wk : Wv);
    float4 v = *(const float4*)(W + (size_t)h * 65536 + (size_t)d * 64 + n4 * 4);
    unsigned short* dst = wt + (size_t)which * 1048576 + ((size_t)h * 64 + n4 * 4) * 1024 + d;
    dst[0]    = f2bf(v.x);
    dst[1024] = f2bf(v.y);
    dst[2048] = f2bf(v.z);
    dst[3072] = f2bf(v.w);
  } else {
    int idx = (blockIdx.x - 3072) * 256 + threadIdx.x;  // [0, 262144)
    int k = idx >> 8;
    int n4 = idx & 255;
    float4 v = *(const float4*)(Wo + (size_t)k * 1024 + n4 * 4);
    unsigned short* dst = wot + ((size_t)n4 * 4) * 1024 + k;
    dst[0]    = f2bf(v.x);
    dst[1024] = f2bf(v.y);
    dst[2048] = f2bf(v.z);
    dst[3072] = f2bf(v.w);
  }
}

// ---------------------------------------------------------------------------
// Kernel 1: per-head projections, 4 heads per block (64 s-rows x 256 n-cols).
// T14 register prefetch (X and W tiles one K-step ahead) + lgkm-only barriers.
// grid (16 s-tiles, 4 head-groups, 12 = which*4+b), block 256.
// ---------------------------------------------------------------------------
__global__ __launch_bounds__(256) void proj_kernel(
    const float* __restrict__ q_in, const float* __restrict__ k_in,
    const float* __restrict__ v_in, const unsigned short* __restrict__ wt,
    unsigned short* __restrict__ qws, unsigned short* __restrict__ kws,
    unsigned short* __restrict__ vws) {
  __shared__ unsigned short lds[(64 + 256) * 72];       // 45 KB -> 3 blocks/CU
  unsigned short* Xs = lds;                             // [64][72]
  unsigned short* Ws = lds + 64 * 72;                   // [256][72]
  const int tid = threadIdx.x;
  const int s0 = blockIdx.x * 64;
  const int hg = blockIdx.y;
  const int b = blockIdx.z & 3;
  const int which = blockIdx.z >> 2;                    // 0=Q 1=K 2=V
  const float* X = which == 0 ? q_in : (which == 1 ? k_in : v_in);
  const unsigned short* wbase = wt + (size_t)which * 1048576 + (size_t)hg * 256 * 1024;
  const int w = tid >> 6, lane = tid & 63, q16 = lane & 15, quad = lane >> 4;

  f32x4 acc[4][4];
  #pragma unroll
  for (int m = 0; m < 4; ++m)
    #pragma unroll
    for (int j = 0; j < 4; ++j) acc[m][j] = (f32x4)0.0f;

  // prefetch kt=0
  float4 xr[4];
  uint4 wreg[8];
  #pragma unroll
  for (int p = 0; p < 4; ++p) {
    int idx = tid + p * 256, r = idx >> 4, c4 = idx & 15;
    xr[p] = *(const float4*)(X + (size_t)(b * 1024 + s0 + r) * 1024 + c4 * 4);
  }
  #pragma unroll
  for (int p = 0; p < 8; ++p) {
    int idx = tid + p * 256, r = idx >> 3, c = idx & 7;
    wreg[p] = *(const uint4*)(wbase + (size_t)r * 1024 + c * 8);
  }

  for (int kt = 0; kt < 16; ++kt) {
    // write prefetched tile to LDS
    #pragma unroll
    for (int p = 0; p < 4; ++p) {
      int idx = tid + p * 256, r = idx >> 4, c4 = idx & 15;
      ushort4 u;
      u.x = f2bf(xr[p].x); u.y = f2bf(xr[p].y); u.z = f2bf(xr[p].z); u.w = f2bf(xr[p].w);
      *(ushort4*)&Xs[r * 72 + c4 * 4] = u;
    }
    #pragma unroll
    for (int p = 0; p < 8; ++p) {
      int idx = tid + p * 256, r = idx >> 3, c = idx & 7;
      *(uint4*)&Ws[r * 72 + c * 8] = wreg[p];
    }
    // issue kt+1 loads; stay in flight across bar_lds
    if (kt < 15) {
      #pragma unroll
      for (int p = 0; p < 4; ++p) {
        int idx = tid + p * 256, r = idx >> 4, c4 = idx & 15;
        xr[p] = *(const float4*)(X + (size_t)(b * 1024 + s0 + r) * 1024 + (kt + 1) * 64 + c4 * 4);
      }
      #pragma unroll
      for (int p = 0; p < 8; ++p) {
        int idx = tid + p * 256, r = idx >> 3, c = idx & 7;
        wreg[p] = *(const uint4*)(wbase + (size_t)r * 1024 + (kt + 1) * 64 + c * 8);
      }
    }
    bar_lds();
    #pragma unroll
    for (int kk = 0; kk < 2; ++kk) {
      short8 a[4];
      #pragma unroll
      for (int m = 0; m < 4; ++m)
        a[m] = *(const short8*)&Xs[(m * 16 + q16) * 72 + kk * 32 + quad * 8];
      #pragma unroll
      for (int j = 0; j < 4; ++j) {
        short8 bb = *(const short8*)&Ws[(w * 64 + j * 16 + q16) * 72 + kk * 32 + quad * 8];
        #pragma unroll
        for (int m = 0; m < 4; ++m)
          acc[m][j] = __builtin_amdgcn_mfma_f32_16x16x32_bf16(a[m], bb, acc[m][j], 0, 0, 0);
      }
    }
    bar_lds();
  }

  // Epilogue: acc -> LDS (bf16) -> coalesced uint4 global stores.
  if (which != 2) {
    unsigned short* Cs = lds;                           // [64][264]
    #pragma unroll
    for (int m = 0; m < 4; ++m)
      #pragma unroll
      for (int j = 0; j < 4; ++j)
        #pragma unroll
        for (int r = 0; r < 4; ++r)
          Cs[(m * 16 + quad * 4 + r) * 264 + w * 64 + j * 16 + q16] = f2bf(acc[m][j][r]);
    __syncthreads();
    unsigned short* dst = which ? kws : qws;
    #pragma unroll
    for (int p = 0; p < 8; ++p) {
      int idx = tid + p * 256;
      int sl = idx >> 5, t = idx & 31;
      int nl = t * 8;
      int head = hg * 4 + (nl >> 6), ko = nl & 63;
      *(uint4*)(dst + ((size_t)((b * 16 + head) * 1024 + s0 + sl)) * 64 + ko) =
          *(const uint4*)&Cs[sl * 264 + nl];
    }
  } else {
    unsigned short* Cs = lds;                           // [256][72], rows = n
    #pragma unroll
    for (int m = 0; m < 4; ++m)
      #pragma unroll
      for (int j = 0; j < 4; ++j)
        #pragma unroll
        for (int r = 0; r < 4; ++r)
          Cs[(w * 64 + j * 16 + q16) * 72 + m * 16 + quad * 4 + r] = f2bf(acc[m][j][r]);
    __syncthreads();
    #pragma unroll
    for (int p = 0; p < 8; ++p) {
      int idx = tid + p * 256;
      int nl = idx >> 3, c = idx & 7;
      int head = hg * 4 + (nl >> 6), d = nl & 63;
      *(uint4*)(vws + ((size_t)((b * 16 + head) * 64 + d)) * 1024 + s0 + c * 8) =
          *(const uint4*)&Cs[nl * 72 + c * 8];
    }
  }
}

// ---------------------------------------------------------------------------
// Kernel 2: flash-style attention per (q-tile 64, h, b).
// T14 depth-1 register pipeline now includes the MASK tile (prefetched like
// K/V, staged to LDS [64][68] int — 2-way conflict-free, readout ds_read_b32).
// Kills 16 dependent scalar global mask loads per lane per K-step.
// Scores stores are non-temporal (write-once, never read -> don't pollute L2).
// grid 1024 linear (XCD swizzle), block 256.  LDS 53 KB -> 3 blocks/CU.
// ---------------------------------------------------------------------------
__global__ __launch_bounds__(256) void attn_kernel(
    const unsigned short* __restrict__ qws, const unsigned short* __restrict__ kws,
    const unsigned short* __restrict__ vws, const int* __restrict__ mask,
    float* __restrict__ scores, unsigned short* __restrict__ cws) {
  __shared__ unsigned short Qs[64 * 72];
  __shared__ unsigned short Ks[64 * 72];
  __shared__ unsigned short Vts[64 * 72];
  __shared__ unsigned short Ps[64 * 72];
  __shared__ int Ms[64 * 68];
  const int tid = threadIdx.x;
  const int L = blockIdx.x;
  const int xcd = L & 7, t = L >> 3;
  const int h = (((t >> 3) & 3) << 2) | (xcd & 3);
  const int qt = ((t & 7) << 1) | (xcd >> 2);
  const int b = t >> 5;
  const int q0 = qt * 64;
  const int w = tid >> 6, lane = tid & 63, q16 = lane & 15, quad = lane >> 4;
  const size_t bh = (size_t)(b * 16 + h);

  const int r1 = tid >> 3, c1 = tid & 7;
  const int r2 = (tid + 256) >> 3;
  const unsigned short* ksrc0 = kws + bh * 1024 * 64;
  const unsigned short* vsrc0 = vws + bh * 64 * 1024;
  const int* msrc0 = mask + ((size_t)b * 1024 + q0) * 1024;

  // stage Q tile once
  {
    const unsigned short* src = qws + (bh * 1024 + q0) * 64;
    *(uint4*)&Qs[r1 * 72 + c1 * 8] = *(const uint4*)(src + r1 * 64 + c1 * 8);
    *(uint4*)&Qs[r2 * 72 + c1 * 8] = *(const uint4*)(src + r2 * 64 + c1 * 8);
  }
  // prefetch kt=0 K/V/mask into registers
  uint4 kr0 = *(const uint4*)(ksrc0 + r1 * 64 + c1 * 8);
  uint4 kr1 = *(const uint4*)(ksrc0 + r2 * 64 + c1 * 8);
  uint4 vr0 = *(const uint4*)(vsrc0 + (size_t)r1 * 1024 + c1 * 8);
  uint4 vr1 = *(const uint4*)(vsrc0 + (size_t)r2 * 1024 + c1 * 8);
  int4 mr[4];
  #pragma unroll
  for (int p = 0; p < 4; ++p) {
    int idx = tid + p * 256, r = idx >> 4, c4 = idx & 15;
    mr[p] = *(const int4*)(msrc0 + (size_t)r * 1024 + c4 * 4);
  }

  bar_lds();
  short8 aq0 = *(const short8*)&Qs[(w * 16 + q16) * 72 + quad * 8];
  short8 aq1 = *(const short8*)&Qs[(w * 16 + q16) * 72 + 32 + quad * 8];

  f32x4 o[4];
  #pragma unroll
  for (int j = 0; j < 4; ++j) o[j] = (f32x4)0.0f;
  float m_run[4] = {-3.0e38f, -3.0e38f, -3.0e38f, -3.0e38f};
  float l_run[4] = {0.f, 0.f, 0.f, 0.f};

  for (int kt = 0; kt < 16; ++kt) {
    // write the prefetched tiles to LDS
    *(uint4*)&Ks[r1 * 72 + c1 * 8] = kr0;
    *(uint4*)&Ks[r2 * 72 + c1 * 8] = kr1;
    *(uint4*)&Vts[r1 * 72 + c1 * 8] = vr0;
    *(uint4*)&Vts[r2 * 72 + c1 * 8] = vr1;
    #pragma unroll
    for (int p = 0; p < 4; ++p) {
      int idx = tid + p * 256, r = idx >> 4, c4 = idx & 15;
      *(int4*)&Ms[r * 68 + c4 * 4] = mr[p];
    }
    // issue next tile's loads; they stay in flight across bar_lds
    if (kt < 15) {
      const unsigned short* ksrc = ksrc0 + (size_t)(kt + 1) * 64 * 64;
      const unsigned short* vsrc = vsrc0 + (kt + 1) * 64;
      kr0 = *(const uint4*)(ksrc + r1 * 64 + c1 * 8);
      kr1 = *(const uint4*)(ksrc + r2 * 64 + c1 * 8);
      vr0 = *(const uint4*)(vsrc + (size_t)r1 * 1024 + c1 * 8);
      vr1 = *(const uint4*)(vsrc + (size_t)r2 * 1024 + c1 * 8);
      #pragma unroll
      for (int p = 0; p < 4; ++p) {
        int idx = tid + p * 256, r = idx >> 4, c4 = idx & 15;
        mr[p] = *(const int4*)(msrc0 + (size_t)r * 1024 + (kt + 1) * 64 + c4 * 4);
      }
    }
    bar_lds();

    // S = Q K^T
    f32x4 sacc[4];
    #pragma unroll
    for (int j = 0; j < 4; ++j) sacc[j] = (f32x4)0.0f;
    #pragma unroll
    for (int j = 0; j < 4; ++j) {
      short8 bb = *(const short8*)&Ks[(j * 16 + q16) * 72 + quad * 8];
      sacc[j] = __builtin_amdgcn_mfma_f32_16x16x32_bf16(aq0, bb, sacc[j], 0, 0, 0);
    }
    #pragma unroll
    for (int j = 0; j < 4; ++j) {
      short8 bb = *(const short8*)&Ks[(j * 16 + q16) * 72 + 32 + quad * 8];
      sacc[j] = __builtin_amdgcn_mfma_f32_16x16x32_bf16(aq1, bb, sacc[j], 0, 0, 0);
    }

    // scale, mask (from LDS), write masked scores (fp32, nt), track row max
    float rm[4] = {-3.0e38f, -3.0e38f, -3.0e38f, -3.0e38f};
    #pragma unroll
    for (int j = 0; j < 4; ++j) {
      #pragma unroll
      for (int r = 0; r < 4; ++r) {
        int ql = w * 16 + quad * 4 + r;
        int q = q0 + ql;
        int key = kt * 64 + j * 16 + q16;
        int mk = Ms[ql * 68 + j * 16 + q16];
        float sv = sacc[j][r] * 0.125f;
        __builtin_nontemporal_store(mk ? sv : -INFINITY,
            &scores[(((size_t)h * 4 + b) * 1024 + q) * 1024 + key]);
        sv = mk ? sv : -3.0e38f;   // finite sentinel for softmax math
        sacc[j][r] = sv;
        rm[r] = fmaxf(rm[r], sv);
      }
    }
    #pragma unroll
    for (int mM = 1; mM <= 8; mM <<= 1) {
      #pragma unroll
      for (int r = 0; r < 4; ++r) rm[r] = fmaxf(rm[r], __shfl_xor(rm[r], mM));
    }
    // T13 defer-max: only rescale when a row max grew by > 8.
    int need = 0;
    #pragma unroll
    for (int r = 0; r < 4; ++r) need |= (rm[r] > m_run[r] + 8.0f);
    if (__any(need)) {
      #pragma unroll
      for (int r = 0; r < 4; ++r) {
        float mnew = fmaxf(m_run[r], rm[r]);
        float alpha = __expf(m_run[r] - mnew);
        m_run[r] = mnew;
        l_run[r] *= alpha;
        #pragma unroll
        for (int j = 0; j < 4; ++j) o[j][r] *= alpha;
      }
    }
    float rs[4] = {0.f, 0.f, 0.f, 0.f};
    // P = exp(S - m), write bf16 to LDS in A-operand row layout (wave-local)
    #pragma unroll
    for (int j = 0; j < 4; ++j) {
      #pragma unroll
      for (int r = 0; r < 4; ++r) {
        float p = __expf(sacc[j][r] - m_run[r]);
        rs[r] += p;
        int ql = w * 16 + quad * 4 + r;
        Ps[ql * 72 + j * 16 + q16] = f2bf(p);
      }
    }
    #pragma unroll
    for (int mM = 1; mM <= 8; mM <<= 1) {
      #pragma unroll
      for (int r = 0; r < 4; ++r) rs[r] += __shfl_xor(rs[r], mM);
    }
    #pragma unroll
    for (int r = 0; r < 4; ++r) l_run[r] += rs[r];

    // O += P V   (no barrier: Ps rows are wave-local)
    #pragma unroll
    for (int kk = 0; kk < 2; ++kk) {
      short8 a = *(const short8*)&Ps[(w * 16 + q16) * 72 + kk * 32 + quad * 8];
      #pragma unroll
      for (int j = 0; j < 4; ++j) {
        short8 bb = *(const short8*)&Vts[(j * 16 + q16) * 72 + kk * 32 + quad * 8];
        o[j] = __builtin_amdgcn_mfma_f32_16x16x32_bf16(a, bb, o[j], 0, 0, 0);
      }
    }
    bar_lds();   // Ks/Vts/Ms free for next iteration's writes
  }

  float inv[4];
  #pragma unroll
  for (int r = 0; r < 4; ++r) inv[r] = 1.0f / l_run[r];
  #pragma unroll
  for (int j = 0; j < 4; ++j) {
    #pragma unroll
    for (int r = 0; r < 4; ++r) {
      int ql = w * 16 + quad * 4 + r;
      int d = j * 16 + q16;
      cws[((size_t)(b * 1024 + q0 + ql)) * 1024 + h * 64 + d] = f2bf(o[j][r] * inv[r]);
    }
  }
}

// ---------------------------------------------------------------------------
// Kernel 3: out = concat(bf16) @ Wo^T(bf16), fp32 out.
// 128x128 tile, 512 threads (8 waves, 2x4), 16 MFMA/wave/K-step,
// T14 register prefetch + lgkm-only barriers, nt stores.
// grid (32 m-tiles, 8 n-tiles), block 512.
// ---------------------------------------------------------------------------
__global__ __launch_bounds__(512) void outproj_kernel(
    const unsigned short* __restrict__ cws, const unsigned short* __restrict__ wot,
    float* __restrict__ out) {
  __shared__ unsigned short As[128 * 72];
  __shared__ unsigned short Bs[128 * 72];
  const int tid = threadIdx.x;
  const int m0 = blockIdx.x * 128;
  const int n0 = blockIdx.y * 128;
  const int w = tid >> 6, lane = tid & 63, q16 = lane & 15, quad = lane >> 4;
  const int wr = w >> 2, wc = w & 3;     // wave owns rows wr*64+[0,64), cols wc*32+[0,32)
  f32x4 acc[4][2];
  #pragma unroll
  for (int m = 0; m < 4; ++m)
    #pragma unroll
    for (int j = 0; j < 2; ++j) acc[m][j] = (f32x4)0.0f;

  // prefetch kt=0
  uint4 ar[2], br[2];
  #pragma unroll
  for (int p = 0; p < 2; ++p) {
    int idx = tid + p * 512, r = idx >> 3, c = idx & 7;
    ar[p] = *(const uint4*)(cws + (size_t)(m0 + r) * 1024 + c * 8);
    br[p] = *(const uint4*)(wot + (size_t)(n0 + r) * 1024 + c * 8);
  }

  for (int kt = 0; kt < 16; ++kt) {
    #pragma unroll
    for (int p = 0; p < 2; ++p) {
      int idx = tid + p * 512, r = idx >> 3, c = idx & 7;
      *(uint4*)&As[r * 72 + c * 8] = ar[p];
      *(uint4*)&Bs[r * 72 + c * 8] = br[p];
    }
    if (kt < 15) {
      #pragma unroll
      for (int p = 0; p < 2; ++p) {
        int idx = tid + p * 512, r = idx >> 3, c = idx & 7;
        ar[p] = *(const uint4*)(cws + (size_t)(m0 + r) * 1024 + (kt + 1) * 64 + c * 8);
        br[p] = *(const uint4*)(wot + (size_t)(n0 + r) * 1024 + (kt + 1) * 64 + c * 8);
      }
    }
    bar_lds();
    #pragma unroll
    for (int kk = 0; kk < 2; ++kk) {
      short8 a[4];
      #pragma unroll
      for (int m = 0; m < 4; ++m)
        a[m] = *(const short8*)&As[(wr * 64 + m * 16 + q16) * 72 + kk * 32 + quad * 8];
      #pragma unroll
      for (int j = 0; j < 2; ++j) {
        short8 bb = *(const short8*)&Bs[(wc * 32 + j * 16 + q16) * 72 + kk * 32 + quad * 8];
        #pragma unroll
        for (int m = 0; m < 4; ++m)
          acc[m][j] = __builtin_amdgcn_mfma_f32_16x16x32_bf16(a[m], bb, acc[m][j], 0, 0, 0);
      }
    }
    bar_lds();
  }
  #pragma unroll
  for (int m = 0; m < 4; ++m) {
    #pragma unroll
    for (int j = 0; j < 2; ++j) {
      #pragma unroll
      for (int r = 0; r < 4; ++r) {
        __builtin_nontemporal_store(acc[m][j][r],
            &out[(size_t)(m0 + wr * 64 + m * 16 + quad * 4 + r) * 1024 +
                 n0 + wc * 32 + j * 16 + q16]);
      }
    }
  }
}

extern "C" void kernel_launch(void* const* d_in, const int* in_sizes, int n_in,
                              void* d_out, int out_size, void* d_ws, size_t ws_size,
                              hipStream_t stream) {
  (void)in_sizes; (void)n_in; (void)out_size; (void)ws_size;
  const float* q_in = (const float*)d_in[0];
  const float* k_in = (const float*)d_in[1];
  const float* v_in = (const float*)d_in[2];
  const int* mask   = (const int*)d_in[3];
  const float* Wq   = (const float*)d_in[4];
  const float* Wk   = (const float*)d_in[5];
  const float* Wv   = (const float*)d_in[6];
  const float* Wo   = (const float*)d_in[7];

  float* out = (float*)d_out;                         // [4,1024,1024]
  float* scores = out + (size_t)4 * 1024 * 1024;      // [16,4,1024,1024]

  // workspace: Q,K,V (bf16, 8.39 MB each) + concat (8.39 MB) + Wo^T (2.1 MB).
  // wt (6.3 MB) aliases the cws region: prep writes it, proj reads it, then
  // attn overwrites cws — strictly stream-ordered.
  unsigned short* qws = (unsigned short*)d_ws;
  unsigned short* kws = qws + (size_t)4 * 16 * 1024 * 64;
  unsigned short* vws = kws + (size_t)4 * 16 * 1024 * 64;
  unsigned short* cws = vws + (size_t)4 * 16 * 1024 * 64;
  unsigned short* wt  = cws;                          // aliased on purpose
  unsigned short* wot = cws + (size_t)4 * 1024 * 1024;  // after cws: survives attn

  prep_wt<<<dim3(4096), 256, 0, stream>>>(Wq, Wk, Wv, Wo, wt, wot);
  proj_kernel<<<dim3(16, 4, 12), 256, 0, stream>>>(q_in, k_in, v_in, wt, qws, kws, vws);
  attn_kernel<<<dim3(1024), 256, 0, stream>>>(qws, kws, vws, mask, scores, cws);
  outproj_kernel<<<dim3(32, 8), 512, 0, stream>>>(cws, wot, out);
}

// Round 6
// 656.672 us; speedup vs baseline: 1.1074x; 1.1074x over previous
//
#include <hip/hip_runtime.h>
#include <hip/hip_bf16.h>
#include <math.h>

typedef __attribute__((ext_vector_type(8))) short short8;
typedef __attribute__((ext_vector_type(4))) float f32x4;

// Problem constants: B=4, S=1024, H=16, d_k=64, d_model=1024.

static __device__ __forceinline__ unsigned short f2bf(float x) {
  union { float f; unsigned u; } v; v.f = x;
  unsigned r = v.u + 0x7fffu + ((v.u >> 16) & 1u);   // RNE
  return (unsigned short)(r >> 16);
}

// lgkmcnt-only barrier: drains LDS traffic (cross-wave LDS reads safe) but
// leaves global register-prefetch loads in flight across the barrier.
static __device__ __forceinline__ void bar_lds() {
  asm volatile("s_waitcnt lgkmcnt(0)" ::: "memory");
  __builtin_amdgcn_s_barrier();
}

// ---------------------------------------------------------------------------
// Kernel 0: prep — transpose+convert weights to bf16.
//   blocks [0,3072): Wq/Wk/Wv -> wt[which][h][n=64][d=1024]  (6.3 MB)
//   blocks [3072,4096): Wo -> wot[n=1024][k=1024]            (2.1 MB)
// ---------------------------------------------------------------------------
__global__ __launch_bounds__(256) void prep_wt(
    const float* __restrict__ Wq, const float* __restrict__ Wk,
    const float* __restrict__ Wv, const float* __restrict__ Wo,
    unsigned short* __restrict__ wt, unsigned short* __restrict__ wot) {
  if (blockIdx.x < 3072) {
    int idx = blockIdx.x * 256 + threadIdx.x;   // [0, 786432)
    int which = idx >> 18;
    int rem = idx & 262143;
    int h = rem >> 14;
    int d = (rem >> 4) & 1023;
    int n4 = rem & 15;
    const float* W = which == 0 ? Wq : (which == 1 ? Wk : Wv);
    float4 v = *(const float4*)(W + (size_t)h * 65536 + (size_t)d * 64 + n4 * 4);
    unsigned short* dst = wt + (size_t)which * 1048576 + ((size_t)h * 64 + n4 * 4) * 1024 + d;
    dst[0]    = f2bf(v.x);
    dst[1024] = f2bf(v.y);
    dst[2048] = f2bf(v.z);
    dst[3072] = f2bf(v.w);
  } else {
    int idx = (blockIdx.x - 3072) * 256 + threadIdx.x;  // [0, 262144)
    int k = idx >> 8;
    int n4 = idx & 255;
    float4 v = *(const float4*)(Wo + (size_t)k * 1024 + n4 * 4);
    unsigned short* dst = wot + ((size_t)n4 * 4) * 1024 + k;
    dst[0]    = f2bf(v.x);
    dst[1024] = f2bf(v.y);
    dst[2048] = f2bf(v.z);
    dst[3072] = f2bf(v.w);
  }
}

// ---------------------------------------------------------------------------
// Kernel 1: per-head projections, 4 heads per block (64 s-rows x 256 n-cols).
// T14 register prefetch (X and W tiles one K-step ahead) + lgkm-only barriers.
// grid (16 s-tiles, 4 head-groups, 12 = which*4+b), block 256.
// ---------------------------------------------------------------------------
__global__ __launch_bounds__(256) void proj_kernel(
    const float* __restrict__ q_in, const float* __restrict__ k_in,
    const float* __restrict__ v_in, const unsigned short* __restrict__ wt,
    unsigned short* __restrict__ qws, unsigned short* __restrict__ kws,
    unsigned short* __restrict__ vws) {
  __shared__ unsigned short lds[(64 + 256) * 72];       // 45 KB -> 3 blocks/CU
  unsigned short* Xs = lds;                             // [64][72]
  unsigned short* Ws = lds + 64 * 72;                   // [256][72]
  const int tid = threadIdx.x;
  const int s0 = blockIdx.x * 64;
  const int hg = blockIdx.y;
  const int b = blockIdx.z & 3;
  const int which = blockIdx.z >> 2;                    // 0=Q 1=K 2=V
  const float* X = which == 0 ? q_in : (which == 1 ? k_in : v_in);
  const unsigned short* wbase = wt + (size_t)which * 1048576 + (size_t)hg * 256 * 1024;
  const int w = tid >> 6, lane = tid & 63, q16 = lane & 15, quad = lane >> 4;

  f32x4 acc[4][4];
  #pragma unroll
  for (int m = 0; m < 4; ++m)
    #pragma unroll
    for (int j = 0; j < 4; ++j) acc[m][j] = (f32x4)0.0f;

  // prefetch kt=0
  float4 xr[4];
  uint4 wreg[8];
  #pragma unroll
  for (int p = 0; p < 4; ++p) {
    int idx = tid + p * 256, r = idx >> 4, c4 = idx & 15;
    xr[p] = *(const float4*)(X + (size_t)(b * 1024 + s0 + r) * 1024 + c4 * 4);
  }
  #pragma unroll
  for (int p = 0; p < 8; ++p) {
    int idx = tid + p * 256, r = idx >> 3, c = idx & 7;
    wreg[p] = *(const uint4*)(wbase + (size_t)r * 1024 + c * 8);
  }

  for (int kt = 0; kt < 16; ++kt) {
    // write prefetched tile to LDS
    #pragma unroll
    for (int p = 0; p < 4; ++p) {
      int idx = tid + p * 256, r = idx >> 4, c4 = idx & 15;
      ushort4 u;
      u.x = f2bf(xr[p].x); u.y = f2bf(xr[p].y); u.z = f2bf(xr[p].z); u.w = f2bf(xr[p].w);
      *(ushort4*)&Xs[r * 72 + c4 * 4] = u;
    }
    #pragma unroll
    for (int p = 0; p < 8; ++p) {
      int idx = tid + p * 256, r = idx >> 3, c = idx & 7;
      *(uint4*)&Ws[r * 72 + c * 8] = wreg[p];
    }
    // issue kt+1 loads; stay in flight across bar_lds
    if (kt < 15) {
      #pragma unroll
      for (int p = 0; p < 4; ++p) {
        int idx = tid + p * 256, r = idx >> 4, c4 = idx & 15;
        xr[p] = *(const float4*)(X + (size_t)(b * 1024 + s0 + r) * 1024 + (kt + 1) * 64 + c4 * 4);
      }
      #pragma unroll
      for (int p = 0; p < 8; ++p) {
        int idx = tid + p * 256, r = idx >> 3, c = idx & 7;
        wreg[p] = *(const uint4*)(wbase + (size_t)r * 1024 + (kt + 1) * 64 + c * 8);
      }
    }
    bar_lds();
    #pragma unroll
    for (int kk = 0; kk < 2; ++kk) {
      short8 a[4];
      #pragma unroll
      for (int m = 0; m < 4; ++m)
        a[m] = *(const short8*)&Xs[(m * 16 + q16) * 72 + kk * 32 + quad * 8];
      #pragma unroll
      for (int j = 0; j < 4; ++j) {
        short8 bb = *(const short8*)&Ws[(w * 64 + j * 16 + q16) * 72 + kk * 32 + quad * 8];
        #pragma unroll
        for (int m = 0; m < 4; ++m)
          acc[m][j] = __builtin_amdgcn_mfma_f32_16x16x32_bf16(a[m], bb, acc[m][j], 0, 0, 0);
      }
    }
    bar_lds();
  }

  // Epilogue: acc -> LDS (bf16) -> coalesced uint4 global stores.
  if (which != 2) {
    unsigned short* Cs = lds;                           // [64][264]
    #pragma unroll
    for (int m = 0; m < 4; ++m)
      #pragma unroll
      for (int j = 0; j < 4; ++j)
        #pragma unroll
        for (int r = 0; r < 4; ++r)
          Cs[(m * 16 + quad * 4 + r) * 264 + w * 64 + j * 16 + q16] = f2bf(acc[m][j][r]);
    __syncthreads();
    unsigned short* dst = which ? kws : qws;
    #pragma unroll
    for (int p = 0; p < 8; ++p) {
      int idx = tid + p * 256;
      int sl = idx >> 5, t = idx & 31;
      int nl = t * 8;
      int head = hg * 4 + (nl >> 6), ko = nl & 63;
      *(uint4*)(dst + ((size_t)((b * 16 + head) * 1024 + s0 + sl)) * 64 + ko) =
          *(const uint4*)&Cs[sl * 264 + nl];
    }
  } else {
    unsigned short* Cs = lds;                           // [256][72], rows = n
    #pragma unroll
    for (int m = 0; m < 4; ++m)
      #pragma unroll
      for (int j = 0; j < 4; ++j)
        #pragma unroll
        for (int r = 0; r < 4; ++r)
          Cs[(w * 64 + j * 16 + q16) * 72 + m * 16 + quad * 4 + r] = f2bf(acc[m][j][r]);
    __syncthreads();
    #pragma unroll
    for (int p = 0; p < 8; ++p) {
      int idx = tid + p * 256;
      int nl = idx >> 3, c = idx & 7;
      int head = hg * 4 + (nl >> 6), d = nl & 63;
      *(uint4*)(vws + ((size_t)((b * 16 + head) * 64 + d)) * 1024 + s0 + c * 8) =
          *(const uint4*)&Cs[nl * 72 + c * 8];
    }
  }
}

// ---------------------------------------------------------------------------
// Kernel 2: flash-style attention per (q-tile 64, h, b).
// R2-verified form: scalar mask loads, plain (cached) scores stores,
// 36 KB LDS -> 4 blocks/CU.  T14 K/V register pipeline, lgkm-only barriers,
// XCD swizzle, defer-max.
// grid 1024 linear, block 256.
// ---------------------------------------------------------------------------
__global__ __launch_bounds__(256) void attn_kernel(
    const unsigned short* __restrict__ qws, const unsigned short* __restrict__ kws,
    const unsigned short* __restrict__ vws, const int* __restrict__ mask,
    float* __restrict__ scores, unsigned short* __restrict__ cws) {
  __shared__ unsigned short Qs[64 * 72];
  __shared__ unsigned short Ks[64 * 72];
  __shared__ unsigned short Vts[64 * 72];
  __shared__ unsigned short Ps[64 * 72];
  const int tid = threadIdx.x;
  // XCD-aware work decode: hw dispatches linear blockIdx round-robin to XCDs.
  const int L = blockIdx.x;
  const int xcd = L & 7, t = L >> 3;
  const int h = (((t >> 3) & 3) << 2) | (xcd & 3);
  const int qt = ((t & 7) << 1) | (xcd >> 2);
  const int b = t >> 5;
  const int q0 = qt * 64;
  const int w = tid >> 6, lane = tid & 63, q16 = lane & 15, quad = lane >> 4;
  const size_t bh = (size_t)(b * 16 + h);

  const int r1 = tid >> 3, c1 = tid & 7;
  const int r2 = (tid + 256) >> 3;
  const unsigned short* ksrc0 = kws + bh * 1024 * 64;
  const unsigned short* vsrc0 = vws + bh * 64 * 1024;

  // stage Q tile once
  {
    const unsigned short* src = qws + (bh * 1024 + q0) * 64;
    *(uint4*)&Qs[r1 * 72 + c1 * 8] = *(const uint4*)(src + r1 * 64 + c1 * 8);
    *(uint4*)&Qs[r2 * 72 + c1 * 8] = *(const uint4*)(src + r2 * 64 + c1 * 8);
  }
  // prefetch kt=0 K/V into registers
  uint4 kr0 = *(const uint4*)(ksrc0 + r1 * 64 + c1 * 8);
  uint4 kr1 = *(const uint4*)(ksrc0 + r2 * 64 + c1 * 8);
  uint4 vr0 = *(const uint4*)(vsrc0 + (size_t)r1 * 1024 + c1 * 8);
  uint4 vr1 = *(const uint4*)(vsrc0 + (size_t)r2 * 1024 + c1 * 8);

  bar_lds();
  short8 aq0 = *(const short8*)&Qs[(w * 16 + q16) * 72 + quad * 8];
  short8 aq1 = *(const short8*)&Qs[(w * 16 + q16) * 72 + 32 + quad * 8];

  f32x4 o[4];
  #pragma unroll
  for (int j = 0; j < 4; ++j) o[j] = (f32x4)0.0f;
  float m_run[4] = {-3.0e38f, -3.0e38f, -3.0e38f, -3.0e38f};
  float l_run[4] = {0.f, 0.f, 0.f, 0.f};

  for (int kt = 0; kt < 16; ++kt) {
    // write the prefetched tile to LDS
    *(uint4*)&Ks[r1 * 72 + c1 * 8] = kr0;
    *(uint4*)&Ks[r2 * 72 + c1 * 8] = kr1;
    *(uint4*)&Vts[r1 * 72 + c1 * 8] = vr0;
    *(uint4*)&Vts[r2 * 72 + c1 * 8] = vr1;
    // issue next tile's loads; they stay in flight across bar_lds
    if (kt < 15) {
      const unsigned short* ksrc = ksrc0 + (size_t)(kt + 1) * 64 * 64;
      const unsigned short* vsrc = vsrc0 + (kt + 1) * 64;
      kr0 = *(const uint4*)(ksrc + r1 * 64 + c1 * 8);
      kr1 = *(const uint4*)(ksrc + r2 * 64 + c1 * 8);
      vr0 = *(const uint4*)(vsrc + (size_t)r1 * 1024 + c1 * 8);
      vr1 = *(const uint4*)(vsrc + (size_t)r2 * 1024 + c1 * 8);
    }
    bar_lds();

    // S = Q K^T
    f32x4 sacc[4];
    #pragma unroll
    for (int j = 0; j < 4; ++j) sacc[j] = (f32x4)0.0f;
    #pragma unroll
    for (int j = 0; j < 4; ++j) {
      short8 bb = *(const short8*)&Ks[(j * 16 + q16) * 72 + quad * 8];
      sacc[j] = __builtin_amdgcn_mfma_f32_16x16x32_bf16(aq0, bb, sacc[j], 0, 0, 0);
    }
    #pragma unroll
    for (int j = 0; j < 4; ++j) {
      short8 bb = *(const short8*)&Ks[(j * 16 + q16) * 72 + 32 + quad * 8];
      sacc[j] = __builtin_amdgcn_mfma_f32_16x16x32_bf16(aq1, bb, sacc[j], 0, 0, 0);
    }

    // scale, mask, write masked scores (fp32, once), track row max
    float rm[4] = {-3.0e38f, -3.0e38f, -3.0e38f, -3.0e38f};
    #pragma unroll
    for (int j = 0; j < 4; ++j) {
      #pragma unroll
      for (int r = 0; r < 4; ++r) {
        int ql = w * 16 + quad * 4 + r;
        int q = q0 + ql;
        int key = kt * 64 + j * 16 + q16;
        int mk = mask[((size_t)b * 1024 + q) * 1024 + key];
        float sv = sacc[j][r] * 0.125f;
        scores[(((size_t)h * 4 + b) * 1024 + q) * 1024 + key] = mk ? sv : -INFINITY;
        sv = mk ? sv : -3.0e38f;   // finite sentinel for softmax math
        sacc[j][r] = sv;
        rm[r] = fmaxf(rm[r], sv);
      }
    }
    #pragma unroll
    for (int mM = 1; mM <= 8; mM <<= 1) {
      #pragma unroll
      for (int r = 0; r < 4; ++r) rm[r] = fmaxf(rm[r], __shfl_xor(rm[r], mM));
    }
    // T13 defer-max: only rescale when a row max grew by > 8.
    int need = 0;
    #pragma unroll
    for (int r = 0; r < 4; ++r) need |= (rm[r] > m_run[r] + 8.0f);
    if (__any(need)) {
      #pragma unroll
      for (int r = 0; r < 4; ++r) {
        float mnew = fmaxf(m_run[r], rm[r]);
        float alpha = __expf(m_run[r] - mnew);
        m_run[r] = mnew;
        l_run[r] *= alpha;
        #pragma unroll
        for (int j = 0; j < 4; ++j) o[j][r] *= alpha;
      }
    }
    float rs[4] = {0.f, 0.f, 0.f, 0.f};
    // P = exp(S - m), write bf16 to LDS in A-operand row layout (wave-local)
    #pragma unroll
    for (int j = 0; j < 4; ++j) {
      #pragma unroll
      for (int r = 0; r < 4; ++r) {
        float p = __expf(sacc[j][r] - m_run[r]);
        rs[r] += p;
        int ql = w * 16 + quad * 4 + r;
        Ps[ql * 72 + j * 16 + q16] = f2bf(p);
      }
    }
    #pragma unroll
    for (int mM = 1; mM <= 8; mM <<= 1) {
      #pragma unroll
      for (int r = 0; r < 4; ++r) rs[r] += __shfl_xor(rs[r], mM);
    }
    #pragma unroll
    for (int r = 0; r < 4; ++r) l_run[r] += rs[r];

    // O += P V   (no barrier: Ps rows are wave-local)
    #pragma unroll
    for (int kk = 0; kk < 2; ++kk) {
      short8 a = *(const short8*)&Ps[(w * 16 + q16) * 72 + kk * 32 + quad * 8];
      #pragma unroll
      for (int j = 0; j < 4; ++j) {
        short8 bb = *(const short8*)&Vts[(j * 16 + q16) * 72 + kk * 32 + quad * 8];
        o[j] = __builtin_amdgcn_mfma_f32_16x16x32_bf16(a, bb, o[j], 0, 0, 0);
      }
    }
    bar_lds();   // Ks/Vts free for next iteration's writes
  }

  float inv[4];
  #pragma unroll
  for (int r = 0; r < 4; ++r) inv[r] = 1.0f / l_run[r];
  #pragma unroll
  for (int j = 0; j < 4; ++j) {
    #pragma unroll
    for (int r = 0; r < 4; ++r) {
      int ql = w * 16 + quad * 4 + r;
      int d = j * 16 + q16;
      cws[((size_t)(b * 1024 + q0 + ql)) * 1024 + h * 64 + d] = f2bf(o[j][r] * inv[r]);
    }
  }
}

// ---------------------------------------------------------------------------
// Kernel 3: out = concat(bf16) @ Wo^T(bf16), fp32 out.
// 128x128 tile, 512 threads (8 waves, 2x4), 16 MFMA/wave/K-step,
// T14 register prefetch + lgkm-only barriers.  Plain stores.
// grid (32 m-tiles, 8 n-tiles), block 512.
// ---------------------------------------------------------------------------
__global__ __launch_bounds__(512) void outproj_kernel(
    const unsigned short* __restrict__ cws, const unsigned short* __restrict__ wot,
    float* __restrict__ out) {
  __shared__ unsigned short As[128 * 72];
  __shared__ unsigned short Bs[128 * 72];
  const int tid = threadIdx.x;
  const int m0 = blockIdx.x * 128;
  const int n0 = blockIdx.y * 128;
  const int w = tid >> 6, lane = tid & 63, q16 = lane & 15, quad = lane >> 4;
  const int wr = w >> 2, wc = w & 3;     // wave owns rows wr*64+[0,64), cols wc*32+[0,32)
  f32x4 acc[4][2];
  #pragma unroll
  for (int m = 0; m < 4; ++m)
    #pragma unroll
    for (int j = 0; j < 2; ++j) acc[m][j] = (f32x4)0.0f;

  // prefetch kt=0
  uint4 ar[2], br[2];
  #pragma unroll
  for (int p = 0; p < 2; ++p) {
    int idx = tid + p * 512, r = idx >> 3, c = idx & 7;
    ar[p] = *(const uint4*)(cws + (size_t)(m0 + r) * 1024 + c * 8);
    br[p] = *(const uint4*)(wot + (size_t)(n0 + r) * 1024 + c * 8);
  }

  for (int kt = 0; kt < 16; ++kt) {
    #pragma unroll
    for (int p = 0; p < 2; ++p) {
      int idx = tid + p * 512, r = idx >> 3, c = idx & 7;
      *(uint4*)&As[r * 72 + c * 8] = ar[p];
      *(uint4*)&Bs[r * 72 + c * 8] = br[p];
    }
    if (kt < 15) {
      #pragma unroll
      for (int p = 0; p < 2; ++p) {
        int idx = tid + p * 512, r = idx >> 3, c = idx & 7;
        ar[p] = *(const uint4*)(cws + (size_t)(m0 + r) * 1024 + (kt + 1) * 64 + c * 8);
        br[p] = *(const uint4*)(wot + (size_t)(n0 + r) * 1024 + (kt + 1) * 64 + c * 8);
      }
    }
    bar_lds();
    #pragma unroll
    for (int kk = 0; kk < 2; ++kk) {
      short8 a[4];
      #pragma unroll
      for (int m = 0; m < 4; ++m)
        a[m] = *(const short8*)&As[(wr * 64 + m * 16 + q16) * 72 + kk * 32 + quad * 8];
      #pragma unroll
      for (int j = 0; j < 2; ++j) {
        short8 bb = *(const short8*)&Bs[(wc * 32 + j * 16 + q16) * 72 + kk * 32 + quad * 8];
        #pragma unroll
        for (int m = 0; m < 4; ++m)
          acc[m][j] = __builtin_amdgcn_mfma_f32_16x16x32_bf16(a[m], bb, acc[m][j], 0, 0, 0);
      }
    }
    bar_lds();
  }
  #pragma unroll
  for (int m = 0; m < 4; ++m) {
    #pragma unroll
    for (int j = 0; j < 2; ++j) {
      #pragma unroll
      for (int r = 0; r < 4; ++r) {
        out[(size_t)(m0 + wr * 64 + m * 16 + quad * 4 + r) * 1024 +
            n0 + wc * 32 + j * 16 + q16] = acc[m][j][r];
      }
    }
  }
}

extern "C" void kernel_launch(void* const* d_in, const int* in_sizes, int n_in,
                              void* d_out, int out_size, void* d_ws, size_t ws_size,
                              hipStream_t stream) {
  (void)in_sizes; (void)n_in; (void)out_size; (void)ws_size;
  const float* q_in = (const float*)d_in[0];
  const float* k_in = (const float*)d_in[1];
  const float* v_in = (const float*)d_in[2];
  const int* mask   = (const int*)d_in[3];
  const float* Wq   = (const float*)d_in[4];
  const float* Wk   = (const float*)d_in[5];
  const float* Wv   = (const float*)d_in[6];
  const float* Wo   = (const float*)d_in[7];

  float* out = (float*)d_out;                         // [4,1024,1024]
  float* scores = out + (size_t)4 * 1024 * 1024;      // [16,4,1024,1024]

  // workspace: Q,K,V (bf16, 8.39 MB each) + concat (8.39 MB) + Wo^T (2.1 MB).
  // wt (6.3 MB) aliases the cws region: prep writes it, proj reads it, then
  // attn overwrites cws — strictly stream-ordered.
  unsigned short* qws = (unsigned short*)d_ws;
  unsigned short* kws = qws + (size_t)4 * 16 * 1024 * 64;
  unsigned short* vws = kws + (size_t)4 * 16 * 1024 * 64;
  unsigned short* cws = vws + (size_t)4 * 16 * 1024 * 64;
  unsigned short* wt  = cws;                          // aliased on purpose
  unsigned short* wot = cws + (size_t)4 * 1024 * 1024;  // after cws: survives attn

  prep_wt<<<dim3(4096), 256, 0, stream>>>(Wq, Wk, Wv, Wo, wt, wot);
  proj_kernel<<<dim3(16, 4, 12), 256, 0, stream>>>(q_in, k_in, v_in, wt, qws, kws, vws);
  attn_kernel<<<dim3(1024), 256, 0, stream>>>(qws, kws, vws, mask, scores, cws);
  outproj_kernel<<<dim3(32, 8), 512, 0, stream>>>(cws, wot, out);
}

// Round 8
// 518.487 us; speedup vs baseline: 1.4026x; 1.2665x over previous
//
#include <hip/hip_runtime.h>
#include <hip/hip_bf16.h>
#include <math.h>

typedef __attribute__((ext_vector_type(8))) short short8;
typedef __attribute__((ext_vector_type(4))) float f32x4;

// Problem constants: B=4, S=1024, H=16, d_k=64, d_model=1024.

static __device__ __forceinline__ unsigned short f2bf(float x) {
  union { float f; unsigned u; } v; v.f = x;
  unsigned r = v.u + 0x7fffu + ((v.u >> 16) & 1u);   // RNE
  return (unsigned short)(r >> 16);
}

// lgkmcnt-only barrier: drains LDS traffic (cross-wave LDS reads safe) but
// leaves global register-prefetch loads in flight across the barrier.
static __device__ __forceinline__ void bar_lds() {
  asm volatile("s_waitcnt lgkmcnt(0)" ::: "memory");
  __builtin_amdgcn_s_barrier();
}

// ---------------------------------------------------------------------------
// Kernel 0: prep — transpose+convert weights to bf16.
//   blocks [0,3072): Wq/Wk/Wv -> wt[which][h][n=64][d=1024]  (6.3 MB)
//   blocks [3072,4096): Wo -> wot[n=1024][k=1024]            (2.1 MB)
// ---------------------------------------------------------------------------
__global__ __launch_bounds__(256) void prep_wt(
    const float* __restrict__ Wq, const float* __restrict__ Wk,
    const float* __restrict__ Wv, const float* __restrict__ Wo,
    unsigned short* __restrict__ wt, unsigned short* __restrict__ wot) {
  if (blockIdx.x < 3072) {
    int idx = blockIdx.x * 256 + threadIdx.x;   // [0, 786432)
    int which = idx >> 18;
    int rem = idx & 262143;
    int h = rem >> 14;
    int d = (rem >> 4) & 1023;
    int n4 = rem & 15;
    const float* W = which == 0 ? Wq : (which == 1 ? Wk : Wv);
    float4 v = *(const float4*)(W + (size_t)h * 65536 + (size_t)d * 64 + n4 * 4);
    unsigned short* dst = wt + (size_t)which * 1048576 + ((size_t)h * 64 + n4 * 4) * 1024 + d;
    dst[0]    = f2bf(v.x);
    dst[1024] = f2bf(v.y);
    dst[2048] = f2bf(v.z);
    dst[3072] = f2bf(v.w);
  } else {
    int idx = (blockIdx.x - 3072) * 256 + threadIdx.x;  // [0, 262144)
    int k = idx >> 8;
    int n4 = idx & 255;
    float4 v = *(const float4*)(Wo + (size_t)k * 1024 + n4 * 4);
    unsigned short* dst = wot + ((size_t)n4 * 4) * 1024 + k;
    dst[0]    = f2bf(v.x);
    dst[1024] = f2bf(v.y);
    dst[2048] = f2bf(v.z);
    dst[3072] = f2bf(v.w);
  }
}

// ---------------------------------------------------------------------------
// Kernel 1: per-head projections, 4 heads per block (64 s-rows x 256 n-cols).
// R2-verified form: in-loop staging (no register prefetch), __syncthreads.
// grid (16 s-tiles, 4 head-groups, 12 = which*4+b), block 256.
// ---------------------------------------------------------------------------
__global__ __launch_bounds__(256) void proj_kernel(
    const float* __restrict__ q_in, const float* __restrict__ k_in,
    const float* __restrict__ v_in, const unsigned short* __restrict__ wt,
    unsigned short* __restrict__ qws, unsigned short* __restrict__ kws,
    unsigned short* __restrict__ vws) {
  __shared__ unsigned short lds[(64 + 256) * 72];       // 45 KB -> 3 blocks/CU
  unsigned short* Xs = lds;                             // [64][72]
  unsigned short* Ws = lds + 64 * 72;                   // [256][72]
  const int tid = threadIdx.x;
  const int s0 = blockIdx.x * 64;
  const int hg = blockIdx.y;                            // heads hg*4 .. hg*4+3
  const int b = blockIdx.z & 3;
  const int which = blockIdx.z >> 2;                    // 0=Q 1=K 2=V
  const float* X = which == 0 ? q_in : (which == 1 ? k_in : v_in);
  const unsigned short* wbase = wt + (size_t)which * 1048576 + (size_t)hg * 256 * 1024;
  const int w = tid >> 6, lane = tid & 63, q16 = lane & 15, quad = lane >> 4;

  f32x4 acc[4][4];
  #pragma unroll
  for (int m = 0; m < 4; ++m)
    #pragma unroll
    for (int j = 0; j < 4; ++j) acc[m][j] = (f32x4)0.0f;

  for (int kt = 0; kt < 16; ++kt) {
    // stage X tile (64 rows x 64 cols), f32 -> bf16
    #pragma unroll
    for (int p = 0; p < 4; ++p) {
      int idx = tid + p * 256;
      int r = idx >> 4, c4 = idx & 15;
      const float4 v = *(const float4*)(X + (size_t)(b * 1024 + s0 + r) * 1024 + kt * 64 + c4 * 4);
      ushort4 u;
      u.x = f2bf(v.x); u.y = f2bf(v.y); u.z = f2bf(v.z); u.w = f2bf(v.w);
      *(ushort4*)&Xs[r * 72 + c4 * 4] = u;
    }
    // stage W^T tile: 256 n-rows x 64 d-cols, straight bf16 copy
    #pragma unroll
    for (int p = 0; p < 8; ++p) {
      int idx = tid + p * 256;
      int r = idx >> 3, c = idx & 7;
      *(uint4*)&Ws[r * 72 + c * 8] = *(const uint4*)(wbase + (size_t)r * 1024 + kt * 64 + c * 8);
    }
    __syncthreads();
    #pragma unroll
    for (int kk = 0; kk < 2; ++kk) {
      short8 a[4];
      #pragma unroll
      for (int m = 0; m < 4; ++m)
        a[m] = *(const short8*)&Xs[(m * 16 + q16) * 72 + kk * 32 + quad * 8];
      #pragma unroll
      for (int j = 0; j < 4; ++j) {
        short8 bb = *(const short8*)&Ws[(w * 64 + j * 16 + q16) * 72 + kk * 32 + quad * 8];
        #pragma unroll
        for (int m = 0; m < 4; ++m)
          acc[m][j] = __builtin_amdgcn_mfma_f32_16x16x32_bf16(a[m], bb, acc[m][j], 0, 0, 0);
      }
    }
    __syncthreads();
  }

  // Epilogue: acc -> LDS (bf16) -> coalesced uint4 global stores.
  // C/D mapping: row = m*16 + quad*4 + r, col = w*64 + j*16 + q16.
  if (which != 2) {
    unsigned short* Cs = lds;                           // [64][264]
    #pragma unroll
    for (int m = 0; m < 4; ++m)
      #pragma unroll
      for (int j = 0; j < 4; ++j)
        #pragma unroll
        for (int r = 0; r < 4; ++r)
          Cs[(m * 16 + quad * 4 + r) * 264 + w * 64 + j * 16 + q16] = f2bf(acc[m][j][r]);
    __syncthreads();
    unsigned short* dst = which ? kws : qws;
    #pragma unroll
    for (int p = 0; p < 8; ++p) {
      int idx = tid + p * 256;
      int sl = idx >> 5, t = idx & 31;
      int nl = t * 8;
      int head = hg * 4 + (nl >> 6), ko = nl & 63;
      *(uint4*)(dst + ((size_t)((b * 16 + head) * 1024 + s0 + sl)) * 64 + ko) =
          *(const uint4*)&Cs[sl * 264 + nl];
    }
  } else {
    unsigned short* Cs = lds;                           // [256][72], rows = n
    #pragma unroll
    for (int m = 0; m < 4; ++m)
      #pragma unroll
      for (int j = 0; j < 4; ++j)
        #pragma unroll
        for (int r = 0; r < 4; ++r)
          Cs[(w * 64 + j * 16 + q16) * 72 + m * 16 + quad * 4 + r] = f2bf(acc[m][j][r]);
    __syncthreads();
    #pragma unroll
    for (int p = 0; p < 8; ++p) {
      int idx = tid + p * 256;
      int nl = idx >> 3, c = idx & 7;
      int head = hg * 4 + (nl >> 6), d = nl & 63;
      *(uint4*)(vws + ((size_t)((b * 16 + head) * 64 + d)) * 1024 + s0 + c * 8) =
          *(const uint4*)&Cs[nl * 72 + c * 8];
    }
  }
}

// ---------------------------------------------------------------------------
// Kernel 2: flash-style attention per (q-tile 64, h, b).
// R2-verified form: T14 K/V register pipeline, lgkm-only barriers, XCD
// swizzle, defer-max, scalar mask loads, plain scores stores.  36 KB LDS.
// grid 1024 linear, block 256.
// ---------------------------------------------------------------------------
__global__ __launch_bounds__(256) void attn_kernel(
    const unsigned short* __restrict__ qws, const unsigned short* __restrict__ kws,
    const unsigned short* __restrict__ vws, const int* __restrict__ mask,
    float* __restrict__ scores, unsigned short* __restrict__ cws) {
  __shared__ unsigned short Qs[64 * 72];
  __shared__ unsigned short Ks[64 * 72];
  __shared__ unsigned short Vts[64 * 72];
  __shared__ unsigned short Ps[64 * 72];
  const int tid = threadIdx.x;
  // XCD-aware work decode: hw dispatches linear blockIdx round-robin to XCDs.
  const int L = blockIdx.x;
  const int xcd = L & 7, t = L >> 3;
  const int h = (((t >> 3) & 3) << 2) | (xcd & 3);
  const int qt = ((t & 7) << 1) | (xcd >> 2);
  const int b = t >> 5;
  const int q0 = qt * 64;
  const int w = tid >> 6, lane = tid & 63, q16 = lane & 15, quad = lane >> 4;
  const size_t bh = (size_t)(b * 16 + h);

  const int r1 = tid >> 3, c1 = tid & 7;
  const int r2 = (tid + 256) >> 3;
  const unsigned short* ksrc0 = kws + bh * 1024 * 64;
  const unsigned short* vsrc0 = vws + bh * 64 * 1024;

  // stage Q tile once
  {
    const unsigned short* src = qws + (bh * 1024 + q0) * 64;
    *(uint4*)&Qs[r1 * 72 + c1 * 8] = *(const uint4*)(src + r1 * 64 + c1 * 8);
    *(uint4*)&Qs[r2 * 72 + c1 * 8] = *(const uint4*)(src + r2 * 64 + c1 * 8);
  }
  // prefetch kt=0 K/V into registers
  uint4 kr0 = *(const uint4*)(ksrc0 + r1 * 64 + c1 * 8);
  uint4 kr1 = *(const uint4*)(ksrc0 + r2 * 64 + c1 * 8);
  uint4 vr0 = *(const uint4*)(vsrc0 + (size_t)r1 * 1024 + c1 * 8);
  uint4 vr1 = *(const uint4*)(vsrc0 + (size_t)r2 * 1024 + c1 * 8);

  bar_lds();
  short8 aq0 = *(const short8*)&Qs[(w * 16 + q16) * 72 + quad * 8];
  short8 aq1 = *(const short8*)&Qs[(w * 16 + q16) * 72 + 32 + quad * 8];

  f32x4 o[4];
  #pragma unroll
  for (int j = 0; j < 4; ++j) o[j] = (f32x4)0.0f;
  float m_run[4] = {-3.0e38f, -3.0e38f, -3.0e38f, -3.0e38f};
  float l_run[4] = {0.f, 0.f, 0.f, 0.f};

  for (int kt = 0; kt < 16; ++kt) {
    // write the prefetched tile to LDS
    *(uint4*)&Ks[r1 * 72 + c1 * 8] = kr0;
    *(uint4*)&Ks[r2 * 72 + c1 * 8] = kr1;
    *(uint4*)&Vts[r1 * 72 + c1 * 8] = vr0;
    *(uint4*)&Vts[r2 * 72 + c1 * 8] = vr1;
    // issue next tile's loads; they stay in flight across bar_lds
    if (kt < 15) {
      const unsigned short* ksrc = ksrc0 + (size_t)(kt + 1) * 64 * 64;
      const unsigned short* vsrc = vsrc0 + (kt + 1) * 64;
      kr0 = *(const uint4*)(ksrc + r1 * 64 + c1 * 8);
      kr1 = *(const uint4*)(ksrc + r2 * 64 + c1 * 8);
      vr0 = *(const uint4*)(vsrc + (size_t)r1 * 1024 + c1 * 8);
      vr1 = *(const uint4*)(vsrc + (size_t)r2 * 1024 + c1 * 8);
    }
    bar_lds();

    // S = Q K^T
    f32x4 sacc[4];
    #pragma unroll
    for (int j = 0; j < 4; ++j) sacc[j] = (f32x4)0.0f;
    #pragma unroll
    for (int j = 0; j < 4; ++j) {
      short8 bb = *(const short8*)&Ks[(j * 16 + q16) * 72 + quad * 8];
      sacc[j] = __builtin_amdgcn_mfma_f32_16x16x32_bf16(aq0, bb, sacc[j], 0, 0, 0);
    }
    #pragma unroll
    for (int j = 0; j < 4; ++j) {
      short8 bb = *(const short8*)&Ks[(j * 16 + q16) * 72 + 32 + quad * 8];
      sacc[j] = __builtin_amdgcn_mfma_f32_16x16x32_bf16(aq1, bb, sacc[j], 0, 0, 0);
    }

    // scale, mask, write masked scores (fp32, once), track row max
    float rm[4] = {-3.0e38f, -3.0e38f, -3.0e38f, -3.0e38f};
    #pragma unroll
    for (int j = 0; j < 4; ++j) {
      #pragma unroll
      for (int r = 0; r < 4; ++r) {
        int ql = w * 16 + quad * 4 + r;
        int q = q0 + ql;
        int key = kt * 64 + j * 16 + q16;
        int mk = mask[((size_t)b * 1024 + q) * 1024 + key];
        float sv = sacc[j][r] * 0.125f;
        scores[(((size_t)h * 4 + b) * 1024 + q) * 1024 + key] = mk ? sv : -INFINITY;
        sv = mk ? sv : -3.0e38f;   // finite sentinel for softmax math
        sacc[j][r] = sv;
        rm[r] = fmaxf(rm[r], sv);
      }
    }
    #pragma unroll
    for (int mM = 1; mM <= 8; mM <<= 1) {
      #pragma unroll
      for (int r = 0; r < 4; ++r) rm[r] = fmaxf(rm[r], __shfl_xor(rm[r], mM));
    }
    // T13 defer-max: only rescale when a row max grew by > 8.
    int need = 0;
    #pragma unroll
    for (int r = 0; r < 4; ++r) need |= (rm[r] > m_run[r] + 8.0f);
    if (__any(need)) {
      #pragma unroll
      for (int r = 0; r < 4; ++r) {
        float mnew = fmaxf(m_run[r], rm[r]);
        float alpha = __expf(m_run[r] - mnew);
        m_run[r] = mnew;
        l_run[r] *= alpha;
        #pragma unroll
        for (int j = 0; j < 4; ++j) o[j][r] *= alpha;
      }
    }
    float rs[4] = {0.f, 0.f, 0.f, 0.f};
    // P = exp(S - m), write bf16 to LDS in A-operand row layout (wave-local)
    #pragma unroll
    for (int j = 0; j < 4; ++j) {
      #pragma unroll
      for (int r = 0; r < 4; ++r) {
        float p = __expf(sacc[j][r] - m_run[r]);
        rs[r] += p;
        int ql = w * 16 + quad * 4 + r;
        Ps[ql * 72 + j * 16 + q16] = f2bf(p);
      }
    }
    #pragma unroll
    for (int mM = 1; mM <= 8; mM <<= 1) {
      #pragma unroll
      for (int r = 0; r < 4; ++r) rs[r] += __shfl_xor(rs[r], mM);
    }
    #pragma unroll
    for (int r = 0; r < 4; ++r) l_run[r] += rs[r];

    // O += P V   (no barrier: Ps rows are wave-local)
    #pragma unroll
    for (int kk = 0; kk < 2; ++kk) {
      short8 a = *(const short8*)&Ps[(w * 16 + q16) * 72 + kk * 32 + quad * 8];
      #pragma unroll
      for (int j = 0; j < 4; ++j) {
        short8 bb = *(const short8*)&Vts[(j * 16 + q16) * 72 + kk * 32 + quad * 8];
        o[j] = __builtin_amdgcn_mfma_f32_16x16x32_bf16(a, bb, o[j], 0, 0, 0);
      }
    }
    bar_lds();   // Ks/Vts free for next iteration's writes
  }

  float inv[4];
  #pragma unroll
  for (int r = 0; r < 4; ++r) inv[r] = 1.0f / l_run[r];
  #pragma unroll
  for (int j = 0; j < 4; ++j) {
    #pragma unroll
    for (int r = 0; r < 4; ++r) {
      int ql = w * 16 + quad * 4 + r;
      int d = j * 16 + q16;
      cws[((size_t)(b * 1024 + q0 + ql)) * 1024 + h * 64 + d] = f2bf(o[j][r] * inv[r]);
    }
  }
}

// ---------------------------------------------------------------------------
// Kernel 3: out = concat(bf16) @ Wo^T(bf16, pre-transposed), fp32 out.
// R2-verified form: 64x64 tile, block 256, Bs pure uint4 copy, __syncthreads.
// grid (64 m-tiles, 16 n-tiles), block 256.
// ---------------------------------------------------------------------------
__global__ __launch_bounds__(256) void outproj_kernel(
    const unsigned short* __restrict__ cws, const unsigned short* __restrict__ wot,
    float* __restrict__ out) {
  __shared__ unsigned short As[64 * 72];
  __shared__ unsigned short Bs[64 * 72];
  const int tid = threadIdx.x;
  const int m0 = blockIdx.x * 64;
  const int n0 = blockIdx.y * 64;
  const int w = tid >> 6, lane = tid & 63, q16 = lane & 15, quad = lane >> 4;
  f32x4 acc[4];
  #pragma unroll
  for (int j = 0; j < 4; ++j) acc[j] = (f32x4)0.0f;

  for (int kt = 0; kt < 16; ++kt) {
    #pragma unroll
    for (int p = 0; p < 2; ++p) {
      int idx = tid + p * 256, r = idx >> 3, c = idx & 7;
      *(uint4*)&As[r * 72 + c * 8] = *(const uint4*)(cws + (size_t)(m0 + r) * 1024 + kt * 64 + c * 8);
      *(uint4*)&Bs[r * 72 + c * 8] = *(const uint4*)(wot + (size_t)(n0 + r) * 1024 + kt * 64 + c * 8);
    }
    __syncthreads();
    #pragma unroll
    for (int kk = 0; kk < 2; ++kk) {
      short8 a = *(const short8*)&As[(w * 16 + q16) * 72 + kk * 32 + quad * 8];
      #pragma unroll
      for (int j = 0; j < 4; ++j) {
        short8 bb = *(const short8*)&Bs[(j * 16 + q16) * 72 + kk * 32 + quad * 8];
        acc[j] = __builtin_amdgcn_mfma_f32_16x16x32_bf16(a, bb, acc[j], 0, 0, 0);
      }
    }
    __syncthreads();
  }
  #pragma unroll
  for (int j = 0; j < 4; ++j) {
    #pragma unroll
    for (int r = 0; r < 4; ++r) {
      out[(size_t)(m0 + w * 16 + quad * 4 + r) * 1024 + n0 + j * 16 + q16] = acc[j][r];
    }
  }
}

extern "C" void kernel_launch(void* const* d_in, const int* in_sizes, int n_in,
                              void* d_out, int out_size, void* d_ws, size_t ws_size,
                              hipStream_t stream) {
  (void)in_sizes; (void)n_in; (void)out_size; (void)ws_size;
  const float* q_in = (const float*)d_in[0];
  const float* k_in = (const float*)d_in[1];
  const float* v_in = (const float*)d_in[2];
  const int* mask   = (const int*)d_in[3];
  const float* Wq   = (const float*)d_in[4];
  const float* Wk   = (const float*)d_in[5];
  const float* Wv   = (const float*)d_in[6];
  const float* Wo   = (const float*)d_in[7];

  float* out = (float*)d_out;                         // [4,1024,1024]
  float* scores = out + (size_t)4 * 1024 * 1024;      // [16,4,1024,1024]

  // workspace: Q,K,V (bf16, 8.39 MB each) + concat (8.39 MB) + Wo^T (2.1 MB).
  // wt (6.3 MB) aliases the cws region: prep writes it, proj reads it, then
  // attn overwrites cws — strictly stream-ordered.
  unsigned short* qws = (unsigned short*)d_ws;
  unsigned short* kws = qws + (size_t)4 * 16 * 1024 * 64;
  unsigned short* vws = kws + (size_t)4 * 16 * 1024 * 64;
  unsigned short* cws = vws + (size_t)4 * 16 * 1024 * 64;
  unsigned short* wt  = cws;                          // aliased on purpose
  unsigned short* wot = cws + (size_t)4 * 1024 * 1024;  // after cws: survives attn

  prep_wt<<<dim3(4096), 256, 0, stream>>>(Wq, Wk, Wv, Wo, wt, wot);
  proj_kernel<<<dim3(16, 4, 12), 256, 0, stream>>>(q_in, k_in, v_in, wt, qws, kws, vws);
  attn_kernel<<<dim3(1024), 256, 0, stream>>>(qws, kws, vws, mask, scores, cws);
  outproj_kernel<<<dim3(64, 16), 256, 0, stream>>>(cws, wot, out);
}